// Round 15
// baseline (214.109 us; speedup 1.0000x reference)
//
#include <hip/hip_runtime.h>

// Problem constants
#define NROWS 512          // N
#define FEAT  8192         // NUM_CHANNELS*4*4
#define BDIM  64
#define CDIM  16
#define MCOLS 1024         // BDIM*CDIM
#define OUTC  8256         // FEAT + BDIM
#define KSPLIT 8
#define KCHUNK (FEAT / KSPLIT)     // 1024
#define KSTEPS (KCHUNK / 64)       // 16
#define MSIZE  (NROWS * MCOLS)     // 524288 floats = 2 MB

typedef __bf16 bf16x8 __attribute__((ext_vector_type(8)));
typedef float  floatx4 __attribute__((ext_vector_type(4)));

// two fp32 -> packed bf16 pair (HW RNE)
static __device__ __forceinline__ unsigned int pk2(float a, float b) {
    unsigned short lo = __builtin_bit_cast(unsigned short, (__bf16)a);
    unsigned short hi = __builtin_bit_cast(unsigned short, (__bf16)b);
    return (unsigned int)lo | ((unsigned int)hi << 16);
}

// ---------------------------------------------------------------------------
// k_gemm: M = x@T (fp32-direct staging, fused bf16 cvt + T-transpose), plus
// x -> out[:, :8192] copy in the 32 blocks with nt == ks.  R12 base verbatim
// (best measured, 126.05): 128x128 tile, 8 waves 2x4, BK=64, split-K=8,
// grid 256, dbuf LDS, raw s_barrier + lgkmcnt(0) only, dist-2 named register
// sets + KEEP pin, Mp layout [ks][b_idx][row][c].
// NEW (R14 post-mortem: NT stores dead; pair's 64MB split-K re-read is the
// last structural redundancy): LAST-BLOCK REDUCTION. Each tile's 8 ks-blocks
// bump a device-scope counter after a release fence; the 8th reduces the 8
// partial slices IN K-ORDER (bit-identical to pair's previous in-order sum)
// into Mfin (2 MB). Wait-free: no spinning, no co-residency assumption.
// flags are zeroed each iteration by hipMemsetAsync in kernel_launch.
// ---------------------------------------------------------------------------
__global__ __launch_bounds__(512, 2) void k_gemm(const float* __restrict__ x,
                                                 const float* __restrict__ T,
                                                 float* __restrict__ Mp,
                                                 float* __restrict__ Mfin,
                                                 int* __restrict__ flags,
                                                 float* __restrict__ out) {
    __shared__ __align__(16) unsigned short ldsA[2][128 * 64];   // 32 KB
    __shared__ __align__(16) unsigned short ldsB[2][128 * 64];   // 32 KB
    __shared__ int lastFlag;
    char* ldsAc = (char*)ldsA;
    char* ldsBc = (char*)ldsB;

    int bid = blockIdx.x;
    int wg = (bid & 7) * 32 + (bid >> 3);        // XCD-contiguous remap; ks==XCD
    int mt = wg & 3, nt = (wg >> 2) & 7, ks = wg >> 5;   // ks in 0..7
    int m0 = mt * 128, n0 = nt * 128, kbase = ks * KCHUNK;
    int t = threadIdx.x, w = t >> 6, l = t & 63;
    bool docopy = (nt == ks);                    // 32 blocks tile x once

    // ---- staging geometry: A rows (k-contiguous, no transpose)
    int arow = t >> 4, aq = t & 15;              // 32 rows (+r*32), 16 k-quads
    const float* gA = x + (size_t)(m0 + arow) * FEAT + kbase + aq * 4;
    float* gC = out + (size_t)(m0 + arow) * OUTC + kbase + aq * 4;
    int swa = (arow & 7) ^ ((arow >> 2) & 7);    // invariant under +32 rows
    int wA = arow * 128 + (((aq >> 1) ^ swa) << 4) + ((aq & 1) << 3);

    // ---- staging geometry: B (transpose T[k][n] -> n-major rows)
    int n4 = t & 31, kg = t >> 5;                // 32 n-quads, 16 k-quads
    const float* gB = T + (size_t)(kbase + kg * 4) * MCOLS + n0 + n4 * 4;
    int wB0, wB1, wB2, wB3;
    {
        int n_0 = n4 * 4 + 0, n_1 = n4 * 4 + 1, n_2 = n4 * 4 + 2, n_3 = n4 * 4 + 3;
        wB0 = n_0 * 128 + (((kg >> 1) ^ ((n_0 & 7) ^ ((n_0 >> 2) & 7))) << 4) + ((kg & 1) << 3);
        wB1 = n_1 * 128 + (((kg >> 1) ^ ((n_1 & 7) ^ ((n_1 >> 2) & 7))) << 4) + ((kg & 1) << 3);
        wB2 = n_2 * 128 + (((kg >> 1) ^ ((n_2 & 7) ^ ((n_2 >> 2) & 7))) << 4) + ((kg & 1) << 3);
        wB3 = n_3 * 128 + (((kg >> 1) ^ ((n_3 & 7) ^ ((n_3 >> 2) & 7))) << 4) + ((kg & 1) << 3);
    }

    // ---- compute geometry: wave (wr=w>>2, wc=w&3) owns 64x32 of C
    int wr = w >> 2, wc = w & 3, fm = l & 15, fq = l >> 4;
    int swf = (fm & 7) ^ ((fm >> 2) & 7);
    int baseA = (wr * 64 + fm) * 128 + ((fq ^ swf) << 4);
    int baseB = (wc * 32 + fm) * 128 + ((fq ^ swf) << 4);

    floatx4 acc[4][2] = {};

    // two named-scalar staging sets (KEEP pins them to distinct registers)
    float4 va00, va01, va02, va03, vb00, vb01, vb02, vb03;
    float4 va10, va11, va12, va13, vb10, vb11, vb12, vb13;

#define ISSUE(A0, A1, A2, A3, B0, B1, B2, B3, KK) do {                      \
        const float* pa_ = gA + (KK) * 64;                                  \
        A0 = *(const float4*)(pa_);                                         \
        A1 = *(const float4*)(pa_ + 32 * FEAT);                             \
        A2 = *(const float4*)(pa_ + 64 * FEAT);                             \
        A3 = *(const float4*)(pa_ + 96 * FEAT);                             \
        const float* pb_ = gB + (size_t)(KK) * 64 * MCOLS;                  \
        B0 = *(const float4*)(pb_);                                         \
        B1 = *(const float4*)(pb_ + MCOLS);                                 \
        B2 = *(const float4*)(pb_ + 2 * MCOLS);                             \
        B3 = *(const float4*)(pb_ + 3 * MCOLS);                             \
    } while (0)

#define KEEP(A0, A1, A2, A3, B0, B1, B2, B3)                                \
    asm volatile("" ::                                                      \
        "v"(A0.x), "v"(A0.y), "v"(A0.z), "v"(A0.w),                         \
        "v"(A1.x), "v"(A1.y), "v"(A1.z), "v"(A1.w),                         \
        "v"(A2.x), "v"(A2.y), "v"(A2.z), "v"(A2.w),                         \
        "v"(A3.x), "v"(A3.y), "v"(A3.z), "v"(A3.w),                         \
        "v"(B0.x), "v"(B0.y), "v"(B0.z), "v"(B0.w),                         \
        "v"(B1.x), "v"(B1.y), "v"(B1.z), "v"(B1.w),                         \
        "v"(B2.x), "v"(B2.y), "v"(B2.z), "v"(B2.w),                         \
        "v"(B3.x), "v"(B3.y), "v"(B3.z), "v"(B3.w))

#define WRITE(A0, A1, A2, A3, B0, B1, B2, B3, SO, KK) do {                  \
        uint2 u_;                                                           \
        u_.x = pk2(A0.x, A0.y); u_.y = pk2(A0.z, A0.w);                     \
        *(uint2*)(ldsAc + (SO) + wA + 0 * 4096) = u_;                       \
        u_.x = pk2(A1.x, A1.y); u_.y = pk2(A1.z, A1.w);                     \
        *(uint2*)(ldsAc + (SO) + wA + 1 * 4096) = u_;                       \
        u_.x = pk2(A2.x, A2.y); u_.y = pk2(A2.z, A2.w);                     \
        *(uint2*)(ldsAc + (SO) + wA + 2 * 4096) = u_;                       \
        u_.x = pk2(A3.x, A3.y); u_.y = pk2(A3.z, A3.w);                     \
        *(uint2*)(ldsAc + (SO) + wA + 3 * 4096) = u_;                       \
        u_.x = pk2(B0.x, B1.x); u_.y = pk2(B2.x, B3.x);                     \
        *(uint2*)(ldsBc + (SO) + wB0) = u_;                                 \
        u_.x = pk2(B0.y, B1.y); u_.y = pk2(B2.y, B3.y);                     \
        *(uint2*)(ldsBc + (SO) + wB1) = u_;                                 \
        u_.x = pk2(B0.z, B1.z); u_.y = pk2(B2.z, B3.z);                     \
        *(uint2*)(ldsBc + (SO) + wB2) = u_;                                 \
        u_.x = pk2(B0.w, B1.w); u_.y = pk2(B2.w, B3.w);                     \
        *(uint2*)(ldsBc + (SO) + wB3) = u_;                                 \
        if (docopy) {                                                       \
            *(float4*)(gC + (size_t)0 * 32 * OUTC + (KK) * 64) = A0;        \
            *(float4*)(gC + (size_t)1 * 32 * OUTC + (KK) * 64) = A1;        \
            *(float4*)(gC + (size_t)2 * 32 * OUTC + (KK) * 64) = A2;        \
            *(float4*)(gC + (size_t)3 * 32 * OUTC + (KK) * 64) = A3;        \
        }                                                                   \
    } while (0)

#define MFMA_PHASE(SO) do {                                                 \
        _Pragma("unroll")                                                   \
        for (int h = 0; h < 2; ++h) {                                       \
            bf16x8 af[4], bfr[2];                                           \
            _Pragma("unroll")                                               \
            for (int a = 0; a < 4; ++a)                                     \
                af[a] = *(const bf16x8*)(ldsAc + (SO) + ((baseA + a * 2048) ^ ((h ^ (a & 1)) << 6))); \
            _Pragma("unroll")                                               \
            for (int b = 0; b < 2; ++b)                                     \
                bfr[b] = *(const bf16x8*)(ldsBc + (SO) + ((baseB + b * 2048) ^ ((h ^ (b & 1)) << 6))); \
            _Pragma("unroll")                                               \
            for (int a = 0; a < 4; ++a)                                     \
                _Pragma("unroll")                                           \
                for (int b = 0; b < 2; ++b)                                 \
                    acc[a][b] = __builtin_amdgcn_mfma_f32_16x16x32_bf16(af[a], bfr[b], acc[a][b], 0, 0, 0); \
        }                                                                   \
    } while (0)

    ISSUE(va00, va01, va02, va03, vb00, vb01, vb02, vb03, 0);
    ISSUE(va10, va11, va12, va13, vb10, vb11, vb12, vb13, 1);
    for (int kk = 0; kk < KSTEPS; kk += 2) {
        WRITE(va00, va01, va02, va03, vb00, vb01, vb02, vb03, 0, kk);
        if (kk + 2 < KSTEPS)
            ISSUE(va00, va01, va02, va03, vb00, vb01, vb02, vb03, kk + 2);
        asm volatile("s_waitcnt lgkmcnt(0)" ::: "memory");
        __builtin_amdgcn_sched_barrier(0);
        __builtin_amdgcn_s_barrier();
        MFMA_PHASE(0);
        KEEP(va10, va11, va12, va13, vb10, vb11, vb12, vb13);
        WRITE(va10, va11, va12, va13, vb10, vb11, vb12, vb13, 16384, kk + 1);
        if (kk + 3 < KSTEPS)
            ISSUE(va10, va11, va12, va13, vb10, vb11, vb12, vb13, kk + 3);
        asm volatile("s_waitcnt lgkmcnt(0)" ::: "memory");
        __builtin_amdgcn_sched_barrier(0);
        __builtin_amdgcn_s_barrier();
        MFMA_PHASE(16384);
        KEEP(va00, va01, va02, va03, vb00, vb01, vb02, vb03);
    }
#undef ISSUE
#undef KEEP
#undef WRITE
#undef MFMA_PHASE

    // epilogue: Mp layout [ks][b_idx][row][c]; b_idx = col>>4, c = fm.
    float* outp = Mp + (size_t)ks * MSIZE;
    int b0 = nt * 8 + wc * 2;                    // (n0 + wc*32) >> 4
    int gr0 = m0 + wr * 64;
#pragma unroll
    for (int a = 0; a < 4; ++a)
#pragma unroll
        for (int r = 0; r < 4; ++r) {
            int row = gr0 + a * 16 + fq * 4 + r;
#pragma unroll
            for (int b = 0; b < 2; ++b)
                outp[(size_t)(b0 + b) * (NROWS * CDIM) + row * CDIM + fm] = acc[a][b][r];
        }

    // ---- last-block split-K reduction (wait-free) ----
    __threadfence();                             // release: partials visible
    __syncthreads();                             // all waves' stores fenced
    if (t == 0) lastFlag = atomicAdd(&flags[wg & 31], 1);
    __syncthreads();
    if (lastFlag == KSPLIT - 1) {
        __threadfence();                         // acquire: see all partials
        int br = nt * 8;                         // tile's 8 b_idx values
#pragma unroll
        for (int u = 0; u < 8; ++u) {
            int pos = u * 2048 + t * 4;          // float idx within 16K tile
            int bi = pos >> 11, inner = pos & 2047;
            size_t off = (size_t)(br + bi) * (NROWS * CDIM) + (size_t)m0 * CDIM + inner;
            float4 s = *(const float4*)(Mp + off);
#pragma unroll
            for (int k2 = 1; k2 < KSPLIT; ++k2) {   // k-order: bit-identical
                float4 v = *(const float4*)(Mp + (size_t)k2 * MSIZE + off);
                s.x += v.x; s.y += v.y; s.z += v.z; s.w += v.w;
            }
            *(float4*)(Mfin + off) = s;
        }
    }
}

// ---------------------------------------------------------------------------
// k_pair: o[i,b] = sum_j exp(-L1(M_i,M_j)) -> out[:, 8192:8256].
// Reads the PRE-REDUCED Mfin [b][j][c]: 32 KB linear stage per block
// (8 MB total vs 64 MB before; the 4 blocks sharing b are same-XCD -> L2).
// Compute part verbatim R12.
// ---------------------------------------------------------------------------
__global__ __launch_bounds__(512, 1) void k_pair(const float* __restrict__ Mfin,
                                                 float* __restrict__ out) {
    __shared__ __align__(16) float ldsM[NROWS * CDIM];   // 32 KB
    __shared__ float partial[8][64];
    int bid = blockIdx.x, t = threadIdx.x;
    int b = bid & 63, itp = bid >> 6;
    const float* slab = Mfin + (size_t)b * (NROWS * CDIM);

#pragma unroll
    for (int p = 0; p < 4; ++p) {
        int idx = t + p * 512;                   // 2048 float4, linear
        float4 s = *(const float4*)(slab + (size_t)idx * 4);
        *(float4*)&ldsM[idx * 4] = s;
    }
    __syncthreads();

    int lane = t & 63, w = t >> 6, g = t >> 8, wg = (t >> 6) & 3;
    int i = (itp * 2 + g) * 64 + lane;
    float4 mi0 = *(const float4*)&ldsM[i * CDIM + 0];
    float4 mi1 = *(const float4*)&ldsM[i * CDIM + 4];
    float4 mi2 = *(const float4*)&ldsM[i * CDIM + 8];
    float4 mi3 = *(const float4*)&ldsM[i * CDIM + 12];

    float acc = 0.0f;
    for (int jj = wg * 128; jj < wg * 128 + 128; ++jj) {
        const float4* rp = (const float4*)&ldsM[jj * CDIM];
        float4 a0 = rp[0], a1 = rp[1], a2 = rp[2], a3 = rp[3];
        float d = fabsf(mi0.x - a0.x) + fabsf(mi0.y - a0.y)
                + fabsf(mi0.z - a0.z) + fabsf(mi0.w - a0.w)
                + fabsf(mi1.x - a1.x) + fabsf(mi1.y - a1.y)
                + fabsf(mi1.z - a1.z) + fabsf(mi1.w - a1.w)
                + fabsf(mi2.x - a2.x) + fabsf(mi2.y - a2.y)
                + fabsf(mi2.z - a2.z) + fabsf(mi2.w - a2.w)
                + fabsf(mi3.x - a3.x) + fabsf(mi3.y - a3.y)
                + fabsf(mi3.z - a3.z) + fabsf(mi3.w - a3.w);
        acc += __expf(-d);
    }
    partial[w][lane] = acc;
    __syncthreads();
    if ((t & 255) < 64) {
        int ii = (itp * 2 + g) * 64 + (t & 63);
        float o = partial[g * 4 + 0][t & 63] + partial[g * 4 + 1][t & 63] +
                  partial[g * 4 + 2][t & 63] + partial[g * 4 + 3][t & 63];
        out[(size_t)ii * OUTC + FEAT + b] = o;
    }
}

// ---------------------------------------------------------------------------
extern "C" void kernel_launch(void* const* d_in, const int* in_sizes, int n_in,
                              void* d_out, int out_size, void* d_ws, size_t ws_size,
                              hipStream_t stream) {
    const float* x = (const float*)d_in[0];      // (512, 8192)
    const float* T = (const float*)d_in[1];      // (8192, 1024)
    float* out = (float*)d_out;                  // (512, 8256)

    // ws layout: Mp 16 MB | Mfin 2 MB | flags 128 B
    float* Mp   = (float*)d_ws;
    float* Mfin = (float*)((char*)d_ws + (16u << 20));
    int*   flags = (int*)((char*)d_ws + (18u << 20));

    hipMemsetAsync(flags, 0, 32 * sizeof(int), stream);
    k_gemm<<<256, 512, 0, stream>>>(x, T, Mp, Mfin, flags, out);
    k_pair<<<256, 512, 0, stream>>>(Mfin, out);
}

// Round 16
// 124.488 us; speedup vs baseline: 1.7199x; 1.7199x over previous
//
#include <hip/hip_runtime.h>

// Problem constants
#define NROWS 512          // N
#define FEAT  8192         // NUM_CHANNELS*4*4
#define BDIM  64
#define CDIM  16
#define MCOLS 1024         // BDIM*CDIM
#define OUTC  8256         // FEAT + BDIM
#define KSPLIT 8
#define KCHUNK (FEAT / KSPLIT)     // 1024
#define KSTEPS (KCHUNK / 64)       // 16
#define MSIZE  (NROWS * MCOLS)     // 524288 floats = 2 MB

typedef __bf16 bf16x8 __attribute__((ext_vector_type(8)));
typedef float  floatx4 __attribute__((ext_vector_type(4)));

// two fp32 -> packed bf16 pair (HW RNE)
static __device__ __forceinline__ unsigned int pk2(float a, float b) {
    unsigned short lo = __builtin_bit_cast(unsigned short, (__bf16)a);
    unsigned short hi = __builtin_bit_cast(unsigned short, (__bf16)b);
    return (unsigned int)lo | ((unsigned int)hi << 16);
}

// ---------------------------------------------------------------------------
// k_gemm: M = x@T, fused fp32->bf16 + T-transpose in staging, plus the
// x -> out[:, :8192] copy fused into the 32 blocks with nt == ks.
// R12 BEST-MEASURED CONFIG RESTORED VERBATIM (126.05 us).
// 128x128 tile, 8 waves 2x4, BK=64, split-K=8, grid 256, launch_bounds(512,2).
// Double-buffered LDS, ONE raw s_barrier per K-step, lgkmcnt(0) only --
// vmcnt never drained in-loop. Dist-2 named register sets + KEEP pin.
// Mp epilogue layout [ks][b_idx][row][c] (pair-friendly, measured +3.5us).
// R15 post-mortem: last-block reduction REVERTED -- device-scope fence +
// atomic + reduce tail cost +88us (k_gemm 41 -> 136us, occupancy halved,
// VGPR 52->84). Cross-block sync in the producer is strictly worse than
// the 64MB re-read it replaced.
// ---------------------------------------------------------------------------
__global__ __launch_bounds__(512, 2) void k_gemm(const float* __restrict__ x,
                                                 const float* __restrict__ T,
                                                 float* __restrict__ Mp,
                                                 float* __restrict__ out) {
    __shared__ __align__(16) unsigned short ldsA[2][128 * 64];   // 32 KB
    __shared__ __align__(16) unsigned short ldsB[2][128 * 64];   // 32 KB
    char* ldsAc = (char*)ldsA;
    char* ldsBc = (char*)ldsB;

    int bid = blockIdx.x;
    int wg = (bid & 7) * 32 + (bid >> 3);        // XCD-contiguous remap
    int mt = wg & 3, nt = (wg >> 2) & 7, ks = wg >> 5;   // ks in 0..7
    int m0 = mt * 128, n0 = nt * 128, kbase = ks * KCHUNK;
    int t = threadIdx.x, w = t >> 6, l = t & 63;
    bool docopy = (nt == ks);                    // 32 blocks tile x once

    // ---- staging geometry: A rows (k-contiguous, no transpose)
    int arow = t >> 4, aq = t & 15;              // 32 rows (+r*32), 16 k-quads
    const float* gA = x + (size_t)(m0 + arow) * FEAT + kbase + aq * 4;
    float* gC = out + (size_t)(m0 + arow) * OUTC + kbase + aq * 4;
    int swa = (arow & 7) ^ ((arow >> 2) & 7);    // invariant under +32 rows
    int wA = arow * 128 + (((aq >> 1) ^ swa) << 4) + ((aq & 1) << 3);

    // ---- staging geometry: B (transpose T[k][n] -> n-major rows)
    int n4 = t & 31, kg = t >> 5;                // 32 n-quads, 16 k-quads
    const float* gB = T + (size_t)(kbase + kg * 4) * MCOLS + n0 + n4 * 4;
    int wB0, wB1, wB2, wB3;
    {
        int n_0 = n4 * 4 + 0, n_1 = n4 * 4 + 1, n_2 = n4 * 4 + 2, n_3 = n4 * 4 + 3;
        wB0 = n_0 * 128 + (((kg >> 1) ^ ((n_0 & 7) ^ ((n_0 >> 2) & 7))) << 4) + ((kg & 1) << 3);
        wB1 = n_1 * 128 + (((kg >> 1) ^ ((n_1 & 7) ^ ((n_1 >> 2) & 7))) << 4) + ((kg & 1) << 3);
        wB2 = n_2 * 128 + (((kg >> 1) ^ ((n_2 & 7) ^ ((n_2 >> 2) & 7))) << 4) + ((kg & 1) << 3);
        wB3 = n_3 * 128 + (((kg >> 1) ^ ((n_3 & 7) ^ ((n_3 >> 2) & 7))) << 4) + ((kg & 1) << 3);
    }

    // ---- compute geometry: wave (wr=w>>2, wc=w&3) owns 64x32 of C
    int wr = w >> 2, wc = w & 3, fm = l & 15, fq = l >> 4;
    int swf = (fm & 7) ^ ((fm >> 2) & 7);
    int baseA = (wr * 64 + fm) * 128 + ((fq ^ swf) << 4);
    int baseB = (wc * 32 + fm) * 128 + ((fq ^ swf) << 4);

    floatx4 acc[4][2] = {};

    // two named-scalar staging sets (KEEP pins them to distinct registers)
    float4 va00, va01, va02, va03, vb00, vb01, vb02, vb03;
    float4 va10, va11, va12, va13, vb10, vb11, vb12, vb13;

#define ISSUE(A0, A1, A2, A3, B0, B1, B2, B3, KK) do {                      \
        const float* pa_ = gA + (KK) * 64;                                  \
        A0 = *(const float4*)(pa_);                                         \
        A1 = *(const float4*)(pa_ + 32 * FEAT);                             \
        A2 = *(const float4*)(pa_ + 64 * FEAT);                             \
        A3 = *(const float4*)(pa_ + 96 * FEAT);                             \
        const float* pb_ = gB + (size_t)(KK) * 64 * MCOLS;                  \
        B0 = *(const float4*)(pb_);                                         \
        B1 = *(const float4*)(pb_ + MCOLS);                                 \
        B2 = *(const float4*)(pb_ + 2 * MCOLS);                             \
        B3 = *(const float4*)(pb_ + 3 * MCOLS);                             \
    } while (0)

#define KEEP(A0, A1, A2, A3, B0, B1, B2, B3)                                \
    asm volatile("" ::                                                      \
        "v"(A0.x), "v"(A0.y), "v"(A0.z), "v"(A0.w),                         \
        "v"(A1.x), "v"(A1.y), "v"(A1.z), "v"(A1.w),                         \
        "v"(A2.x), "v"(A2.y), "v"(A2.z), "v"(A2.w),                         \
        "v"(A3.x), "v"(A3.y), "v"(A3.z), "v"(A3.w),                         \
        "v"(B0.x), "v"(B0.y), "v"(B0.z), "v"(B0.w),                         \
        "v"(B1.x), "v"(B1.y), "v"(B1.z), "v"(B1.w),                         \
        "v"(B2.x), "v"(B2.y), "v"(B2.z), "v"(B2.w),                         \
        "v"(B3.x), "v"(B3.y), "v"(B3.z), "v"(B3.w))

#define WRITE(A0, A1, A2, A3, B0, B1, B2, B3, SO, KK) do {                  \
        uint2 u_;                                                           \
        u_.x = pk2(A0.x, A0.y); u_.y = pk2(A0.z, A0.w);                     \
        *(uint2*)(ldsAc + (SO) + wA + 0 * 4096) = u_;                       \
        u_.x = pk2(A1.x, A1.y); u_.y = pk2(A1.z, A1.w);                     \
        *(uint2*)(ldsAc + (SO) + wA + 1 * 4096) = u_;                       \
        u_.x = pk2(A2.x, A2.y); u_.y = pk2(A2.z, A2.w);                     \
        *(uint2*)(ldsAc + (SO) + wA + 2 * 4096) = u_;                       \
        u_.x = pk2(A3.x, A3.y); u_.y = pk2(A3.z, A3.w);                     \
        *(uint2*)(ldsAc + (SO) + wA + 3 * 4096) = u_;                       \
        u_.x = pk2(B0.x, B1.x); u_.y = pk2(B2.x, B3.x);                     \
        *(uint2*)(ldsBc + (SO) + wB0) = u_;                                 \
        u_.x = pk2(B0.y, B1.y); u_.y = pk2(B2.y, B3.y);                     \
        *(uint2*)(ldsBc + (SO) + wB1) = u_;                                 \
        u_.x = pk2(B0.z, B1.z); u_.y = pk2(B2.z, B3.z);                     \
        *(uint2*)(ldsBc + (SO) + wB2) = u_;                                 \
        u_.x = pk2(B0.w, B1.w); u_.y = pk2(B2.w, B3.w);                     \
        *(uint2*)(ldsBc + (SO) + wB3) = u_;                                 \
        if (docopy) {                                                       \
            *(float4*)(gC + (size_t)0 * 32 * OUTC + (KK) * 64) = A0;        \
            *(float4*)(gC + (size_t)1 * 32 * OUTC + (KK) * 64) = A1;        \
            *(float4*)(gC + (size_t)2 * 32 * OUTC + (KK) * 64) = A2;        \
            *(float4*)(gC + (size_t)3 * 32 * OUTC + (KK) * 64) = A3;        \
        }                                                                   \
    } while (0)

#define MFMA_PHASE(SO) do {                                                 \
        _Pragma("unroll")                                                   \
        for (int h = 0; h < 2; ++h) {                                       \
            bf16x8 af[4], bfr[2];                                           \
            _Pragma("unroll")                                               \
            for (int a = 0; a < 4; ++a)                                     \
                af[a] = *(const bf16x8*)(ldsAc + (SO) + ((baseA + a * 2048) ^ ((h ^ (a & 1)) << 6))); \
            _Pragma("unroll")                                               \
            for (int b = 0; b < 2; ++b)                                     \
                bfr[b] = *(const bf16x8*)(ldsBc + (SO) + ((baseB + b * 2048) ^ ((h ^ (b & 1)) << 6))); \
            _Pragma("unroll")                                               \
            for (int a = 0; a < 4; ++a)                                     \
                _Pragma("unroll")                                           \
                for (int b = 0; b < 2; ++b)                                 \
                    acc[a][b] = __builtin_amdgcn_mfma_f32_16x16x32_bf16(af[a], bfr[b], acc[a][b], 0, 0, 0); \
        }                                                                   \
    } while (0)

    ISSUE(va00, va01, va02, va03, vb00, vb01, vb02, vb03, 0);
    ISSUE(va10, va11, va12, va13, vb10, vb11, vb12, vb13, 1);
    for (int kk = 0; kk < KSTEPS; kk += 2) {
        // ---- step kk (buffer 0, set 0)
        WRITE(va00, va01, va02, va03, vb00, vb01, vb02, vb03, 0, kk);
        if (kk + 2 < KSTEPS)
            ISSUE(va00, va01, va02, va03, vb00, vb01, vb02, vb03, kk + 2);
        asm volatile("s_waitcnt lgkmcnt(0)" ::: "memory");
        __builtin_amdgcn_sched_barrier(0);
        __builtin_amdgcn_s_barrier();
        MFMA_PHASE(0);
        KEEP(va10, va11, va12, va13, vb10, vb11, vb12, vb13);   // set1 ready
        // ---- step kk+1 (buffer 1, set 1)
        WRITE(va10, va11, va12, va13, vb10, vb11, vb12, vb13, 16384, kk + 1);
        if (kk + 3 < KSTEPS)
            ISSUE(va10, va11, va12, va13, vb10, vb11, vb12, vb13, kk + 3);
        asm volatile("s_waitcnt lgkmcnt(0)" ::: "memory");
        __builtin_amdgcn_sched_barrier(0);
        __builtin_amdgcn_s_barrier();
        MFMA_PHASE(16384);
        KEEP(va00, va01, va02, va03, vb00, vb01, vb02, vb03);   // set0 ready
    }
#undef ISSUE
#undef KEEP
#undef WRITE
#undef MFMA_PHASE

    // epilogue: Mp layout [ks][b_idx][row][c]; b_idx = col>>4, c = fm.
    float* outp = Mp + (size_t)ks * MSIZE;
    int b0 = nt * 8 + wc * 2;                    // (n0 + wc*32) >> 4
    int gr0 = m0 + wr * 64;
#pragma unroll
    for (int a = 0; a < 4; ++a)
#pragma unroll
        for (int r = 0; r < 4; ++r) {
            int row = gr0 + a * 16 + fq * 4 + r;
#pragma unroll
            for (int b = 0; b < 2; ++b)
                outp[(size_t)(b0 + b) * (NROWS * CDIM) + row * CDIM + fm] = acc[a][b][r];
        }
}

// ---------------------------------------------------------------------------
// k_pair: o[i,b] = sum_j exp(-L1(M_i,M_j)) -> out[:, 8192:8256].
// Mp is [ks][b][j][c] -> staging is 8 fully-linear coalesced streams per
// block (slab + k*MSIZE + idx*4); the 4 blocks sharing b are same-XCD -> L2.
// ldsM [512][16]; compute reads row jj wave-uniform -> broadcast.
// Split-K sum order k=0..7 -> bit-identical output.
// ---------------------------------------------------------------------------
__global__ __launch_bounds__(512, 1) void k_pair(const float* __restrict__ Mp,
                                                 float* __restrict__ out) {
    __shared__ __align__(16) float ldsM[NROWS * CDIM];   // 32 KB
    __shared__ float partial[8][64];
    int bid = blockIdx.x, t = threadIdx.x;
    int b = bid & 63, itp = bid >> 6;
    const float* slab = Mp + (size_t)b * (NROWS * CDIM);

#pragma unroll
    for (int p = 0; p < 4; ++p) {
        int idx = t + p * 512;                   // 2048 float4, linear
        float4 s = *(const float4*)(slab + (size_t)idx * 4);
#pragma unroll
        for (int k = 1; k < KSPLIT; ++k) {
            float4 v = *(const float4*)(slab + (size_t)k * MSIZE + (size_t)idx * 4);
            s.x += v.x; s.y += v.y; s.z += v.z; s.w += v.w;
        }
        *(float4*)&ldsM[idx * 4] = s;
    }
    __syncthreads();

    int lane = t & 63, w = t >> 6, g = t >> 8, wg = (t >> 6) & 3;
    int i = (itp * 2 + g) * 64 + lane;
    float4 mi0 = *(const float4*)&ldsM[i * CDIM + 0];
    float4 mi1 = *(const float4*)&ldsM[i * CDIM + 4];
    float4 mi2 = *(const float4*)&ldsM[i * CDIM + 8];
    float4 mi3 = *(const float4*)&ldsM[i * CDIM + 12];

    float acc = 0.0f;
    for (int jj = wg * 128; jj < wg * 128 + 128; ++jj) {
        const float4* rp = (const float4*)&ldsM[jj * CDIM];
        float4 a0 = rp[0], a1 = rp[1], a2 = rp[2], a3 = rp[3];
        float d = fabsf(mi0.x - a0.x) + fabsf(mi0.y - a0.y)
                + fabsf(mi0.z - a0.z) + fabsf(mi0.w - a0.w)
                + fabsf(mi1.x - a1.x) + fabsf(mi1.y - a1.y)
                + fabsf(mi1.z - a1.z) + fabsf(mi1.w - a1.w)
                + fabsf(mi2.x - a2.x) + fabsf(mi2.y - a2.y)
                + fabsf(mi2.z - a2.z) + fabsf(mi2.w - a2.w)
                + fabsf(mi3.x - a3.x) + fabsf(mi3.y - a3.y)
                + fabsf(mi3.z - a3.z) + fabsf(mi3.w - a3.w);
        acc += __expf(-d);
    }
    partial[w][lane] = acc;
    __syncthreads();
    if ((t & 255) < 64) {
        int ii = (itp * 2 + g) * 64 + (t & 63);
        float o = partial[g * 4 + 0][t & 63] + partial[g * 4 + 1][t & 63] +
                  partial[g * 4 + 2][t & 63] + partial[g * 4 + 3][t & 63];
        out[(size_t)ii * OUTC + FEAT + b] = o;
    }
}

// ---------------------------------------------------------------------------
extern "C" void kernel_launch(void* const* d_in, const int* in_sizes, int n_in,
                              void* d_out, int out_size, void* d_ws, size_t ws_size,
                              hipStream_t stream) {
    const float* x = (const float*)d_in[0];      // (512, 8192)
    const float* T = (const float*)d_in[1];      // (8192, 1024)
    float* out = (float*)d_out;                  // (512, 8256)

    // ws layout: Mp 8 x 2MB = 16 MB at offset 0, [ks][b][j][c]
    float* Mp = (float*)d_ws;

    k_gemm<<<256, 512, 0, stream>>>(x, T, Mp, out);
    k_pair<<<256, 512, 0, stream>>>(Mp, out);
}